// Round 7
// baseline (595.391 us; speedup 1.0000x reference)
//
#include <hip/hip_runtime.h>
#include <cstdint>

// Problem constants
constexpr int N = 8192, E = 262144, D = 128, O = 64, C = 4096;

#define DEV __device__ __forceinline__

typedef short s8v __attribute__((ext_vector_type(8)));   // 8 bf16 (4 VGPRs)
typedef float f4v __attribute__((ext_vector_type(4)));   // MFMA 16x16 accumulator

// orderable-uint mapping for float packed argmax
DEV unsigned fmap(float f) {
  unsigned u = __float_as_uint(f);
  return (u & 0x80000000u) ? ~u : (u | 0x80000000u);
}
DEV float funmap(unsigned u) {  // inverse of fmap
  unsigned o = (u & 0x80000000u) ? (u & 0x7FFFFFFFu) : ~u;
  return __uint_as_float(o);
}
DEV unsigned short f2bf(float f) {  // RNE float->bf16 (finite inputs)
  uint32_t b = __float_as_uint(f);
  return (unsigned short)((b + 0x7FFFu + ((b >> 16) & 1u)) >> 16);
}
DEV float bf2f(unsigned short h) { return __uint_as_float((uint32_t)h << 16); }

// ---------------- setup kernels ----------------

__global__ __launch_bounds__(256) void k_degree(const int* __restrict__ src, const int* __restrict__ dst,
    uint32_t* __restrict__ bits, int* __restrict__ dego, int* __restrict__ degi,
    uint32_t* __restrict__ scal_u) {
  int e = blockIdx.x * 256 + threadIdx.x;
  int s = src[e], d = dst[e];
  atomicAdd(&dego[s], 1);
  atomicAdd(&degi[d], 1);
  unsigned idx = (unsigned)s * 8192u + (unsigned)d;
  unsigned bit = 1u << (idx & 31);
  unsigned old = atomicOr(&bits[idx >> 5], bit);
  bool isnew = !(old & bit);
  unsigned long long b = __ballot(isnew);
  if ((threadIdx.x & 63) == 0) atomicAdd(&scal_u[2], (unsigned)__popcll(b));
}

// exclusive scan of deg_in -> row_ptr/cursor; also both degree norms (k_norms folded in)
__global__ __launch_bounds__(1024) void k_scan(const int* __restrict__ degi, const int* __restrict__ dego,
    int* __restrict__ rowptr, int* __restrict__ cursor,
    float* __restrict__ nsrc, float* __restrict__ ndst) {
  __shared__ int sh[1024];
  int tid = threadIdx.x;
  int base = tid * 8;
  int v[8];
  int s = 0;
#pragma unroll
  for (int j = 0; j < 8; ++j) {
    v[j] = degi[base + j];
    int a = dego[base + j];
    nsrc[base + j] = a > 0 ? 1.0f / sqrtf((float)a) : 0.0f;
    ndst[base + j] = v[j] > 0 ? 1.0f / sqrtf((float)v[j]) : 0.0f;
    s += v[j];
  }
  sh[tid] = s;
  __syncthreads();
  for (int off = 1; off < 1024; off <<= 1) {
    int t = (tid >= off) ? sh[tid - off] : 0;
    __syncthreads();
    sh[tid] += t;
    __syncthreads();
  }
  int run = (tid == 0) ? 0 : sh[tid - 1];
#pragma unroll
  for (int j = 0; j < 8; ++j) { rowptr[base + j] = run; cursor[base + j] = run; run += v[j]; }
  if (tid == 1023) rowptr[N] = run;
}

__global__ __launch_bounds__(256) void k_scatter(const int* __restrict__ src, const int* __restrict__ dst,
                                                 int* __restrict__ cursor, int* __restrict__ csr) {
  int e = blockIdx.x * 256 + threadIdx.x;
  int d = dst[e];
  int pos = atomicAdd(&cursor[d], 1);
  csr[pos] = src[e];
}

// fused scale+aggregate: out[row,:] = (sum_e x[src_e,:]*nsrc[src_e]) * ndst[row]
// __fmul_rn/__fadd_rn forbid fma-contraction -> bit-identical across refactors
// (matters for h1 -> argmax stability).
__global__ __launch_bounds__(128) void k_aggscale(const int* __restrict__ rowptr, const int* __restrict__ csr,
    const float* __restrict__ x, const float* __restrict__ nsrc, const float* __restrict__ ndst,
    float* __restrict__ out) {
  int row = blockIdx.x, t = threadIdx.x;
  int e0 = rowptr[row], e1 = rowptr[row + 1];
  float acc = 0.f;
  int e = e0;
  for (; e + 4 <= e1; e += 4) {
    int s0 = csr[e], s1 = csr[e + 1], s2 = csr[e + 2], s3 = csr[e + 3];
    float n0 = nsrc[s0], n1 = nsrc[s1], n2 = nsrc[s2], n3 = nsrc[s3];
    acc = __fadd_rn(acc, __fmul_rn(x[s0 * 128 + t], n0));
    acc = __fadd_rn(acc, __fmul_rn(x[s1 * 128 + t], n1));
    acc = __fadd_rn(acc, __fmul_rn(x[s2 * 128 + t], n2));
    acc = __fadd_rn(acc, __fmul_rn(x[s3 * 128 + t], n3));
  }
  for (; e < e1; ++e) acc = __fadd_rn(acc, __fmul_rn(x[csr[e] * 128 + t], nsrc[csr[e]]));
  out[row * 128 + t] = __fmul_rn(acc, ndst[row]);
}

// merged row-wise l2 normalize + bf16 hi/lo split for BOTH codebook (rows [0,C)) and
// h1 (rows [C,C+N)). Branch is wave-uniform; each path's math is byte-identical to the
// previously-validated k_l2ns, so all outputs are bit-identical. -1 dispatch.
__global__ __launch_bounds__(256) void k_l2nsb(
    const float* __restrict__ cb, float* __restrict__ cnws, float* __restrict__ o_cn,
    ushort2* __restrict__ chi, ushort2* __restrict__ clo,
    const float* __restrict__ h1, float* __restrict__ xn,
    ushort2* __restrict__ xhi, ushort2* __restrict__ xlo) {
  int wave = threadIdx.x >> 6, lane = threadIdx.x & 63;
  int row = blockIdx.x * 4 + wave;           // [0, C+N)
  const float* in;
  float* out_al;
  float* out_extra;
  ushort2* hi;
  ushort2* lo;
  int r;
  if (row < C) {
    in = cb; out_al = cnws; out_extra = o_cn; hi = chi; lo = clo; r = row;
  } else {
    in = h1; out_al = xn; out_extra = nullptr; hi = xhi; lo = xlo; r = row - C;
  }
  float2 v = ((const float2*)in)[r * 64 + lane];
  float ss = v.x * v.x + v.y * v.y;
#pragma unroll
  for (int o = 32; o > 0; o >>= 1) ss += __shfl_xor(ss, o);
  float den = fmaxf(sqrtf(ss), 1e-12f);
  float ox = v.x / den, oy = v.y / den;
  ((float2*)out_al)[r * 64 + lane] = make_float2(ox, oy);
  if (out_extra != nullptr) {
    out_extra[r * 128 + 2 * lane] = ox;
    out_extra[r * 128 + 2 * lane + 1] = oy;
  }
  ushort2 h, l;
  h.x = f2bf(ox); h.y = f2bf(oy);
  l.x = f2bf(ox - bf2f(h.x)); l.y = f2bf(oy - bf2f(h.y));
  hi[r * 64 + lane] = h;
  lo[r * 64 + lane] = l;
}

// codebook transpose: cnws[4096][128] -> cnwsT[128][4096] (coalesced k_fix loads)
__global__ __launch_bounds__(256) void k_transpose(const float* __restrict__ in, float* __restrict__ outT) {
  __shared__ float tl[64][133];
  int t = threadIdx.x;
  int cbase = blockIdx.x * 64;
#pragma unroll
  for (int it = 0; it < 32; ++it) {
    int idx = t + it * 256;
    int r = idx >> 7, k = idx & 127;
    tl[r][k] = in[(cbase + r) * 128 + k];
  }
  __syncthreads();
#pragma unroll
  for (int it = 0; it < 32; ++it) {
    int idx = t + it * 256;
    int k = idx >> 6, c = idx & 63;
    outT[k * 4096 + cbase + c] = tl[c][k];
  }
}

// ---------------- small matmul: out[M,CO] = A[M,128] @ W[128,CO] + bias (+relu) ----------------
template <int CO, bool RELU>
__global__ __launch_bounds__(256, 2) void k_mm(const float* __restrict__ A, const float* __restrict__ W,
    const float* __restrict__ bias, float* __restrict__ out) {
  constexpr int CG = CO / 4;
  constexpr int RG = 256 / CG;
  constexpr int TR = RG * 4;
  constexpr int WIT = (64 * CG) / 256;
  __shared__ __align__(16) float Al[TR * 128];
  __shared__ __align__(16) float Wl[64 * CO];
  int tid = threadIdx.x;
  int cg = tid % CG, rg = tid / CG;
  int rbase = blockIdx.x * TR;
#pragma unroll
  for (int it = 0; it < TR / 8; ++it) {
    int idx = tid + it * 256;
    int r = idx >> 5, c = idx & 31;
    *(float4*)&Al[r * 128 + c * 4] = *(const float4*)&A[(rbase + r) * 128 + c * 4];
  }
  float acc[4][4] = {};
  for (int kc = 0; kc < 128; kc += 64) {
    __syncthreads();
#pragma unroll
    for (int it = 0; it < WIT; ++it) {
      int idx = tid + it * 256;
      int r = idx / CG, c = idx % CG;
      *(float4*)&Wl[r * CO + c * 4] = *(const float4*)&W[(kc + r) * CO + c * 4];
    }
    __syncthreads();
#pragma unroll
    for (int k = 0; k < 64; ++k) {
      float4 w4 = *(const float4*)&Wl[k * CO + cg * 4];
#pragma unroll
      for (int i = 0; i < 4; ++i) {
        float a = Al[(rg * 4 + i) * 128 + kc + k];
        acc[i][0] += a * w4.x; acc[i][1] += a * w4.y; acc[i][2] += a * w4.z; acc[i][3] += a * w4.w;
      }
    }
  }
  float4 b4 = *(const float4*)&bias[cg * 4];
#pragma unroll
  for (int i = 0; i < 4; ++i) {
    float4 o;
    o.x = acc[i][0] + b4.x; o.y = acc[i][1] + b4.y; o.z = acc[i][2] + b4.z; o.w = acc[i][3] + b4.w;
    if (RELU) { o.x = fmaxf(o.x, 0.f); o.y = fmaxf(o.y, 0.f); o.z = fmaxf(o.z, 0.f); o.w = fmaxf(o.w, 0.f); }
    *(float4*)&out[(rbase + rg * 4 + i) * CO + cg * 4] = o;
  }
}

// fused decoders: qe = q@dec1W+b (fp32 + bf16 copy), frec partial of (h1 - (q@dec2W+b))^2.
__global__ __launch_bounds__(256, 3) void k_dec(const float* __restrict__ A,
    const float* __restrict__ W1, const float* __restrict__ b1,
    const float* __restrict__ W2, const float* __restrict__ b2,
    const float* __restrict__ h1, float* __restrict__ qe, unsigned short* __restrict__ qb,
    float* __restrict__ ps) {
  __shared__ __align__(16) float Al[32 * 128];
  __shared__ __align__(16) float Wl1[32 * 128];
  __shared__ __align__(16) float Wl2[32 * 128];
  int tid = threadIdx.x;
  int cg = tid & 31, rg = tid >> 5;
  int rbase = blockIdx.x * 32;
#pragma unroll
  for (int it = 0; it < 4; ++it) {
    int idx = tid + it * 256;
    int r = idx >> 5, c = idx & 31;
    *(float4*)&Al[r * 128 + c * 4] = *(const float4*)&A[(rbase + r) * 128 + c * 4];
  }
  float acc1[4][4] = {}, acc2[4][4] = {};
  for (int kc = 0; kc < 128; kc += 32) {
    __syncthreads();
#pragma unroll
    for (int it = 0; it < 4; ++it) {
      int idx = tid + it * 256;
      int r = idx >> 5, c = idx & 31;
      *(float4*)&Wl1[r * 128 + c * 4] = *(const float4*)&W1[(kc + r) * 128 + c * 4];
      *(float4*)&Wl2[r * 128 + c * 4] = *(const float4*)&W2[(kc + r) * 128 + c * 4];
    }
    __syncthreads();
#pragma unroll
    for (int k = 0; k < 32; ++k) {
      float4 w1 = *(const float4*)&Wl1[k * 128 + cg * 4];
      float4 w2 = *(const float4*)&Wl2[k * 128 + cg * 4];
#pragma unroll
      for (int i = 0; i < 4; ++i) {
        float a = Al[(rg * 4 + i) * 128 + kc + k];
        acc1[i][0] += a * w1.x; acc1[i][1] += a * w1.y; acc1[i][2] += a * w1.z; acc1[i][3] += a * w1.w;
        acc2[i][0] += a * w2.x; acc2[i][1] += a * w2.y; acc2[i][2] += a * w2.z; acc2[i][3] += a * w2.w;
      }
    }
  }
  float4 bb1 = *(const float4*)&b1[cg * 4];
  float4 bb2 = *(const float4*)&b2[cg * 4];
  float s = 0.f;
#pragma unroll
  for (int i = 0; i < 4; ++i) {
    int row = rbase + rg * 4 + i;
    float4 o;
    o.x = acc1[i][0] + bb1.x; o.y = acc1[i][1] + bb1.y;
    o.z = acc1[i][2] + bb1.z; o.w = acc1[i][3] + bb1.w;
    *(float4*)&qe[row * 128 + cg * 4] = o;
    ushort4 ob;
    ob.x = f2bf(o.x); ob.y = f2bf(o.y); ob.z = f2bf(o.z); ob.w = f2bf(o.w);
    *(ushort4*)&qb[row * 128 + cg * 4] = ob;
    float4 h = *(const float4*)&h1[row * 128 + cg * 4];
    float d0 = acc2[i][0] + bb2.x - h.x;
    float d1 = acc2[i][1] + bb2.y - h.y;
    float d2 = acc2[i][2] + bb2.z - h.z;
    float d3 = acc2[i][3] + bb2.w - h.w;
    s += d0 * d0 + d1 * d1 + d2 * d2 + d3 * d3;
  }
#pragma unroll
  for (int o = 32; o > 0; o >>= 1) s += __shfl_xor(s, o);
  __syncthreads();
  float* shp = Al;
  if ((tid & 63) == 0) shp[tid >> 6] = s;
  __syncthreads();
  if (tid == 0) ps[blockIdx.x] = shp[0] + shp[1] + shp[2] + shp[3];
}

// ---------------- dist via split-bf16 MFMA: dist = xn @ cn^T, hi*hi + hi*lo + lo*hi ----------------
// Round-7 change (ONLY change vs validated round-6 build): dout stores use
// __builtin_nontemporal_store — same addresses, same values, nt cache-bypass bit set.
// dist (134 MB) is write-once/never-re-read; bypassing L2 stops it evicting the
// heavily-reused chi/clo B-tiles (64x reuse across row-tile blocks).
__global__ __launch_bounds__(256) void k_dist(
    const unsigned short* __restrict__ xhi, const unsigned short* __restrict__ xlo,
    const unsigned short* __restrict__ chi, const unsigned short* __restrict__ clo,
    float* __restrict__ dout, unsigned long long* __restrict__ pbk, float* __restrict__ pbv2) {
  int bx = blockIdx.x, by = blockIdx.y;     // bx: codebook tile (32), by: node tile (64)
  int rbase = by * 128, cbase = bx * 128;
  __shared__ __align__(16) unsigned short As[128 * 132];  // +4 pad: conflict-free ds_read_b128
  __shared__ __align__(16) unsigned short Bs[128 * 132];
  int tid = threadIdx.x;
  int wave = tid >> 6, lane = tid & 63;
  int l15 = lane & 15, quad = lane >> 4;
  int wr = wave * 32;

  // stage A-hi and B-hi
#pragma unroll
  for (int it = 0; it < 8; ++it) {
    int idx = tid + it * 256;
    int r = idx >> 4, ch = idx & 15;
    *(s8v*)&As[r * 132 + ch * 8] = *(const s8v*)&xhi[(rbase + r) * 128 + ch * 8];
    *(s8v*)&Bs[r * 132 + ch * 8] = *(const s8v*)&chi[(cbase + r) * 128 + ch * 8];
  }
  __syncthreads();
  s8v ah[2][4], al[2][4];
#pragma unroll
  for (int rt = 0; rt < 2; ++rt)
#pragma unroll
    for (int kq = 0; kq < 4; ++kq)
      ah[rt][kq] = *(const s8v*)&As[(wr + rt * 16 + l15) * 132 + kq * 32 + quad * 8];
  __syncthreads();           // all waves have a-hi frags in regs -> safe to overwrite As
#pragma unroll
  for (int it = 0; it < 8; ++it) {
    int idx = tid + it * 256;
    int r = idx >> 4, ch = idx & 15;
    *(s8v*)&As[r * 132 + ch * 8] = *(const s8v*)&xlo[(rbase + r) * 128 + ch * 8];
  }
  __syncthreads();
#pragma unroll
  for (int rt = 0; rt < 2; ++rt)
#pragma unroll
    for (int kq = 0; kq < 4; ++kq)
      al[rt][kq] = *(const s8v*)&As[(wr + rt * 16 + l15) * 132 + kq * 32 + quad * 8];

  f4v acc[2][8];
#pragma unroll
  for (int rt = 0; rt < 2; ++rt)
#pragma unroll
    for (int ct = 0; ct < 8; ++ct) acc[rt][ct] = {0.f, 0.f, 0.f, 0.f};

  // pass 1+2: (a_hi + a_lo) x B_hi
#pragma unroll
  for (int ct = 0; ct < 8; ++ct) {
    s8v b[4];
#pragma unroll
    for (int kq = 0; kq < 4; ++kq)
      b[kq] = *(const s8v*)&Bs[(ct * 16 + l15) * 132 + kq * 32 + quad * 8];
#pragma unroll
    for (int rt = 0; rt < 2; ++rt)
#pragma unroll
      for (int kq = 0; kq < 4; ++kq) {
        acc[rt][ct] = __builtin_amdgcn_mfma_f32_16x16x32_bf16(ah[rt][kq], b[kq], acc[rt][ct], 0, 0, 0);
        acc[rt][ct] = __builtin_amdgcn_mfma_f32_16x16x32_bf16(al[rt][kq], b[kq], acc[rt][ct], 0, 0, 0);
      }
  }
  __syncthreads();           // all waves done with B_hi -> restage
#pragma unroll
  for (int it = 0; it < 8; ++it) {
    int idx = tid + it * 256;
    int r = idx >> 4, ch = idx & 15;
    *(s8v*)&Bs[r * 132 + ch * 8] = *(const s8v*)&clo[(cbase + r) * 128 + ch * 8];
  }
  __syncthreads();
  // pass 3: a_hi x B_lo
#pragma unroll
  for (int ct = 0; ct < 8; ++ct) {
    s8v b[4];
#pragma unroll
    for (int kq = 0; kq < 4; ++kq)
      b[kq] = *(const s8v*)&Bs[(ct * 16 + l15) * 132 + kq * 32 + quad * 8];
#pragma unroll
    for (int rt = 0; rt < 2; ++rt)
#pragma unroll
      for (int kq = 0; kq < 4; ++kq)
        acc[rt][ct] = __builtin_amdgcn_mfma_f32_16x16x32_bf16(ah[rt][kq], b[kq], acc[rt][ct], 0, 0, 0);
  }

  // epilogue: store dist (nontemporal) + per-lane top2 over the 8 cols each (rt,reg)-row sees
  float b1v[2][4], b2v[2][4];
  unsigned c1v[2][4];
#pragma unroll
  for (int rt = 0; rt < 2; ++rt)
#pragma unroll
    for (int reg = 0; reg < 4; ++reg) { b1v[rt][reg] = -3.4e38f; b2v[rt][reg] = -3.4e38f; c1v[rt][reg] = 0; }
#pragma unroll
  for (int rt = 0; rt < 2; ++rt)
#pragma unroll
    for (int ct = 0; ct < 8; ++ct)
#pragma unroll
      for (int reg = 0; reg < 4; ++reg) {
        float v = acc[rt][ct][reg];
        int row = rbase + wr + rt * 16 + quad * 4 + reg;
        int col = cbase + ct * 16 + l15;
        __builtin_nontemporal_store(v, &dout[(size_t)row * 4096 + col]);  // write-once, never re-read
        if (v > b1v[rt][reg]) { b2v[rt][reg] = b1v[rt][reg]; b1v[rt][reg] = v; c1v[rt][reg] = (unsigned)col; }
        else if (v > b2v[rt][reg]) b2v[rt][reg] = v;  // strict > keeps lowest col (np tie rule)
      }
  __syncthreads();           // As/Bs frag reads all done -> reuse as scratch
  unsigned long long* sck = (unsigned long long*)As;  // [128][16] keys, 16 KB
  float* scv = (float*)Bs;                            // [128][16] 2nd-best values, 8 KB
#pragma unroll
  for (int rt = 0; rt < 2; ++rt)
#pragma unroll
    for (int reg = 0; reg < 4; ++reg) {
      int rloc = wr + rt * 16 + quad * 4 + reg;
      sck[rloc * 16 + l15] =
          (((unsigned long long)fmap(b1v[rt][reg])) << 32) |
          (unsigned long long)(0xFFFFFFFFu - c1v[rt][reg]);
      scv[rloc * 16 + l15] = b2v[rt][reg];
    }
  __syncthreads();
  if (tid < 128) {
    unsigned long long m = 0ull;
#pragma unroll
    for (int l = 0; l < 16; ++l) {
      unsigned long long t = sck[tid * 16 + l];
      m = t > m ? t : m;
    }
    float v2 = -3.4e38f;
#pragma unroll
    for (int l = 0; l < 16; ++l) {
      unsigned long long k = sck[tid * 16 + l];
      float c = (k == m) ? scv[tid * 16 + l] : funmap((unsigned)(k >> 32));
      v2 = fmaxf(v2, c);
    }
    pbk[(size_t)(rbase + tid) * 32 + bx] = m;
    pbv2[(size_t)(rbase + tid) * 32 + bx] = v2;
  }
}

// resolve argmax; ALWAYS finalize with candidate col; near-ties (gap < 2e-4) get appended
// to a worklist for k_fix (round-1 lesson: in-block uncoalesced recompute -> 160us tail).
__global__ __launch_bounds__(128) void k_q(const unsigned long long* __restrict__ pbk,
    const float* __restrict__ pbv2, const float* __restrict__ cnws,
    const float* __restrict__ h1, float* __restrict__ qout, float* __restrict__ pq,
    uint32_t* __restrict__ scal_u, int* __restrict__ flagged) {
  int row = blockIdx.x, t = threadIdx.x;
  int e = t & 31;
  unsigned long long k = pbk[(size_t)row * 32 + e];
  float v2l = pbv2[(size_t)row * 32 + e];
  unsigned long long m = k;
#pragma unroll
  for (int o = 32; o > 0; o >>= 1) {
    unsigned long long s = __shfl_xor(m, o);
    m = s > m ? s : m;
  }
  float cand = (k == m) ? v2l : funmap((unsigned)(k >> 32));
#pragma unroll
  for (int o = 32; o > 0; o >>= 1) cand = fmaxf(cand, __shfl_xor(cand, o));
  float gap = funmap((unsigned)(m >> 32)) - cand;
  if (gap < 2e-4f && t == 0) {
    unsigned idx = atomicAdd(&scal_u[3], 1u);
    flagged[idx] = row;
  }
  int col = (int)(0xFFFFFFFFu - (unsigned)(m & 0xFFFFFFFFull));
  float q = cnws[col * 128 + t];
  qout[row * 128 + t] = q;
  float dd = q - h1[row * 128 + t];
  float ss = dd * dd;
#pragma unroll
  for (int o = 32; o > 0; o >>= 1) ss += __shfl_xor(ss, o);
  __shared__ float p[2];
  if ((t & 63) == 0) p[t >> 6] = ss;
  __syncthreads();
  if (t == 0) pq[row] = p[0] + p[1];
}

// exact fp32 argmax for flagged rows, coalesced via transposed codebook.
__global__ __launch_bounds__(256) void k_fix(const uint32_t* __restrict__ scal_u,
    const int* __restrict__ flagged, const float* __restrict__ xn,
    const float* __restrict__ cnwsT, const float* __restrict__ cnws,
    const float* __restrict__ h1, float* __restrict__ qout, float* __restrict__ pq) {
  int nf = (int)scal_u[3];
  int t = threadIdx.x;
  __shared__ float xr[128];
  __shared__ unsigned long long bw4[4];
  __shared__ float pp[2];
  for (int i = blockIdx.x; i < nf; i += gridDim.x) {
    int row = flagged[i];
    __syncthreads();
    if (t < 128) xr[t] = xn[row * 128 + t];
    __syncthreads();
    float s[16];
#pragma unroll
    for (int j = 0; j < 16; ++j) s[j] = 0.f;
    for (int k = 0; k < 128; ++k) {
      float xv = xr[k];
      const float* cp = &cnwsT[k * 4096 + t];
#pragma unroll
      for (int j = 0; j < 16; ++j) s[j] = fmaf(xv, cp[j * 256], s[j]);
    }
    unsigned long long best = 0ull;
#pragma unroll
    for (int j = 0; j < 16; ++j) {
      unsigned c = (unsigned)(j * 256 + t);
      unsigned long long key = (((unsigned long long)fmap(s[j])) << 32) |
                               (unsigned long long)(0xFFFFFFFFu - c);
      if (key > best) best = key;
    }
#pragma unroll
    for (int o = 32; o > 0; o >>= 1) {
      unsigned long long s2 = __shfl_xor(best, o);
      best = s2 > best ? s2 : best;
    }
    if ((t & 63) == 0) bw4[t >> 6] = best;
    __syncthreads();
    unsigned long long b0 = bw4[0] > bw4[1] ? bw4[0] : bw4[1];
    unsigned long long b1 = bw4[2] > bw4[3] ? bw4[2] : bw4[3];
    best = b0 > b1 ? b0 : b1;
    int col = (int)(0xFFFFFFFFu - (unsigned)(best & 0xFFFFFFFFull));
    if (t < 128) {
      float q = cnws[col * 128 + t];
      qout[(size_t)row * 128 + t] = q;
      float dd = q - h1[row * 128 + t];
      float ss = dd * dd;
#pragma unroll
      for (int o = 32; o > 0; o >>= 1) ss += __shfl_xor(ss, o);
      if ((t & 63) == 0) pp[t >> 6] = ss;
    }
    __syncthreads();
    if (t == 0) pq[row] = pp[0] + pp[1];
  }
}

// ---------------- adjq via bf16 MFMA: fused loss reductions over qe @ qe^T ----------------
__global__ __launch_bounds__(256) void k_adjq(const unsigned short* __restrict__ qb,
    const uint32_t* __restrict__ bits,
    double* __restrict__ p_sum, double* __restrict__ p_sq, double* __restrict__ p_es,
    float* __restrict__ p_mn, float* __restrict__ p_mx) {
  int bx = blockIdx.x, by = blockIdx.y;
  int pid = by * gridDim.x + bx;
  int tid = threadIdx.x;
  if (bx < by) {
    if (tid == 0) {
      p_sum[pid] = 0.0; p_sq[pid] = 0.0; p_es[pid] = 0.0;
      p_mn[pid] = 3.4e38f; p_mx[pid] = -3.4e38f;
    }
    return;
  }
  int rbase = by * 128, cbase = bx * 128;
  __shared__ unsigned short Ab[128 * 132];
  __shared__ unsigned short Bb[128 * 132];
#pragma unroll
  for (int it = 0; it < 8; ++it) {
    int idx = tid + it * 256;
    int r = idx >> 4, ch = idx & 15;
    *(s8v*)&Ab[r * 132 + ch * 8] = *(const s8v*)&qb[(rbase + r) * 128 + ch * 8];
    *(s8v*)&Bb[r * 132 + ch * 8] = *(const s8v*)&qb[(cbase + r) * 128 + ch * 8];
  }
  __syncthreads();
  int wave = tid >> 6, lane = tid & 63;
  int l15 = lane & 15, quad = lane >> 4;
  int wr = wave * 32;
  f4v acc[2][8];
#pragma unroll
  for (int rt = 0; rt < 2; ++rt)
#pragma unroll
    for (int ct = 0; ct < 8; ++ct) acc[rt][ct] = {0.f, 0.f, 0.f, 0.f};
  s8v a[2][4];
#pragma unroll
  for (int rt = 0; rt < 2; ++rt)
#pragma unroll
    for (int kq = 0; kq < 4; ++kq)
      a[rt][kq] = *(const s8v*)&Ab[(wr + rt * 16 + l15) * 132 + kq * 32 + quad * 8];
#pragma unroll
  for (int ct = 0; ct < 8; ++ct) {
    s8v b[4];
#pragma unroll
    for (int kq = 0; kq < 4; ++kq)
      b[kq] = *(const s8v*)&Bb[(ct * 16 + l15) * 132 + kq * 32 + quad * 8];
#pragma unroll
    for (int rt = 0; rt < 2; ++rt)
#pragma unroll
      for (int kq = 0; kq < 4; ++kq)
        acc[rt][ct] = __builtin_amdgcn_mfma_f32_16x16x32_bf16(a[rt][kq], b[kq], acc[rt][ct], 0, 0, 0);
  }
  __syncthreads();
  uint32_t* bl = (uint32_t*)Ab;
  uint32_t* blT = bl + 512;
#pragma unroll
  for (int it = 0; it < 2; ++it) {
    int idx = tid + it * 256;
    int r = idx >> 2, wq = idx & 3;
    bl[idx] = bits[(rbase + r) * 256 + (cbase >> 5) + wq];
    blT[idx] = bits[(cbase + r) * 256 + (rbase >> 5) + wq];
  }
  __syncthreads();
  float lsum = 0.f, lsq = 0.f, les = 0.f;
  float lmin = 3.4e38f, lmax = -3.4e38f;
  bool diag = (bx == by);
#pragma unroll
  for (int rt = 0; rt < 2; ++rt)
#pragma unroll
    for (int ct = 0; ct < 8; ++ct)
#pragma unroll
      for (int reg = 0; reg < 4; ++reg) {
        int lr = wr + rt * 16 + quad * 4 + reg;
        int lc = ct * 16 + l15;
        if (diag && lc < lr) continue;
        float v = acc[rt][ct][reg];
        bool ondiag = diag && (lc == lr);
        float wgt = ondiag ? 1.f : 2.f;
        lsum += wgt * v;
        lsq += wgt * v * v;
        lmin = fminf(lmin, v);
        lmax = fmaxf(lmax, v);
        unsigned eb = (bl[lr * 4 + (lc >> 5)] >> (lc & 31)) & 1u;
        if (!ondiag) eb += (blT[lc * 4 + (lr >> 5)] >> (lr & 31)) & 1u;
        if (eb) les += (float)eb * v;
      }
  double dsum = (double)lsum, dsq = (double)lsq, des = (double)les;
#pragma unroll
  for (int o = 32; o > 0; o >>= 1) {
    dsum += __shfl_xor(dsum, o);
    dsq += __shfl_xor(dsq, o);
    des += __shfl_xor(des, o);
    lmin = fminf(lmin, __shfl_xor(lmin, o));
    lmax = fmaxf(lmax, __shfl_xor(lmax, o));
  }
  double* shd = (double*)Bb;
  float* shf = (float*)(shd + 12);
  if (lane == 0) {
    shd[wave * 3 + 0] = dsum; shd[wave * 3 + 1] = dsq; shd[wave * 3 + 2] = des;
    shf[wave * 2 + 0] = lmin; shf[wave * 2 + 1] = lmax;
  }
  __syncthreads();
  if (tid == 0) {
    double s = 0.0, q = 0.0, e = 0.0;
    float m0 = 3.4e38f, m1 = -3.4e38f;
#pragma unroll
    for (int w0 = 0; w0 < 4; ++w0) {
      s += shd[w0 * 3 + 0]; q += shd[w0 * 3 + 1]; e += shd[w0 * 3 + 2];
      m0 = fminf(m0, shf[w0 * 2 + 0]); m1 = fmaxf(m1, shf[w0 * 2 + 1]);
    }
    p_sum[pid] = s; p_sq[pid] = q; p_es[pid] = e;
    p_mn[pid] = m0; p_mx[pid] = m1;
  }
}

__global__ __launch_bounds__(1024) void k_finish(const double* __restrict__ p_sum,
    const double* __restrict__ p_sq, const double* __restrict__ p_es,
    const float* __restrict__ p_mn, const float* __restrict__ p_mx,
    const float* __restrict__ pq, const float* __restrict__ ps,
    const uint32_t* __restrict__ scal_u, float* __restrict__ o_loss) {
  int tid = threadIdx.x;
  double sum = 0.0, sq = 0.0, es = 0.0, commit = 0.0, frec = 0.0;
  float mn = 3.4e38f, mx = -3.4e38f;
  for (int i = tid; i < 4096; i += 1024) {
    sum += p_sum[i]; sq += p_sq[i]; es += p_es[i];
    mn = fminf(mn, p_mn[i]); mx = fmaxf(mx, p_mx[i]);
  }
  for (int i = tid; i < 8192; i += 1024) commit += (double)pq[i];
  if (tid < 256) frec = (double)ps[tid];   // k_dec emits 256 partials
#pragma unroll
  for (int o = 32; o > 0; o >>= 1) {
    sum += __shfl_xor(sum, o); sq += __shfl_xor(sq, o); es += __shfl_xor(es, o);
    commit += __shfl_xor(commit, o); frec += __shfl_xor(frec, o);
    mn = fminf(mn, __shfl_xor(mn, o)); mx = fmaxf(mx, __shfl_xor(mx, o));
  }
  __shared__ double shd[16][5];
  __shared__ float shf[16][2];
  int wave = tid >> 6, lane = tid & 63;
  if (lane == 0) {
    shd[wave][0] = sum; shd[wave][1] = sq; shd[wave][2] = es;
    shd[wave][3] = commit; shd[wave][4] = frec;
    shf[wave][0] = mn; shf[wave][1] = mx;
  }
  __syncthreads();
  if (tid == 0) {
    double s = 0, q = 0, e = 0, c = 0, f = 0;
    float m0 = 3.4e38f, m1 = -3.4e38f;
    for (int w0 = 0; w0 < 16; ++w0) {
      s += shd[w0][0]; q += shd[w0][1]; e += shd[w0][2]; c += shd[w0][3]; f += shd[w0][4];
      m0 = fminf(m0, shf[w0][0]); m1 = fmaxf(m1, shf[w0][1]);
    }
    double mnd = (double)m0, mxd = (double)m1, U = (double)scal_u[2];
    const double N2 = 67108864.0;
    double scl = 1.0 / (mxd - mnd);
    double mean = (scl * scl * (q - 2.0 * mnd * s + mnd * mnd * N2) - 2.0 * scl * (e - mnd * U) + U) / N2;
    *o_loss = (float)(f / 1048576.0 + sqrt(mean) + 0.25 * c / 1048576.0);
  }
}

extern "C" void kernel_launch(void* const* d_in, const int* in_sizes, int n_in,
                              void* d_out, int out_size, void* d_ws, size_t ws_size,
                              hipStream_t stream) {
  (void)in_sizes; (void)n_in; (void)out_size;
  const float* feats = (const float*)d_in[0];
  const int* src = (const int*)d_in[1];
  const int* dst = (const int*)d_in[2];
  const float* W1 = (const float*)d_in[3];
  const float* b1 = (const float*)d_in[4];
  const float* W2 = (const float*)d_in[5];
  const float* b2 = (const float*)d_in[6];
  const float* dec1W = (const float*)d_in[7];
  const float* dec1b = (const float*)d_in[8];
  const float* dec2W = (const float*)d_in[9];
  const float* dec2b = (const float*)d_in[10];
  const float* linW = (const float*)d_in[11];
  const float* linb = (const float*)d_in[12];
  const float* codebook = (const float*)d_in[13];

  float* out = (float*)d_out;
  float* o_h1 = out;                    // [N,128]
  float* o_q = out + 1048576;           // [N,128]
  float* o_h3 = out + 2097152;          // [N,128]
  float* o_out = out + 3145728;         // [N,64]
  float* o_loss = out + 3670016;        // scalar
  float* o_dist = out + 3670017;        // [N,4096] (float-misaligned base!)
  float* o_cn = out + 37224449;         // [C,128]  (float-misaligned base!)

  char* w = (char*)d_ws;
  size_t off = 0;
  auto alloc = [&](size_t b) { char* p = w + off; off = (off + b + 255) & ~(size_t)255; return p; };
  uint32_t* bits = (uint32_t*)alloc(8388608);            // N*N/8 adjacency bitmask
  int* dego = (int*)alloc(N * 4);
  int* degi = (int*)alloc(N * 4);
  uint32_t* scal_u = (uint32_t*)alloc(256);              // [2]=U unique edges, [3]=flag count
  size_t zero_bytes = off;                               // everything above must start at 0
  int* rowptr = (int*)alloc((N + 1) * 4);
  int* cursor = (int*)alloc(N * 4);
  int* csr = (int*)alloc(E * 4);
  float* nsrc = (float*)alloc(N * 4);
  float* ndst = (float*)alloc(N * 4);
  float* tmp = (float*)alloc((size_t)N * D * 4);         // hosts cnwsT + qb (disjoint live ranges)
  float* agg = (float*)alloc((size_t)N * D * 4);
  float* xn = (float*)alloc((size_t)N * D * 4);
  float* cnws = (float*)alloc((size_t)C * D * 4);        // aligned copy of cn
  float* qe = (float*)alloc((size_t)N * D * 4);
  float* qn = (float*)alloc((size_t)N * D * 4);          // hosts chi/clo alias only
  double* p_sum = (double*)alloc(4096 * 8);              // adjq per-block partials
  double* p_sq = (double*)alloc(4096 * 8);
  double* p_es = (double*)alloc(4096 * 8);
  float* p_mn = (float*)alloc(4096 * 4);
  float* p_mx = (float*)alloc(4096 * 4);
  float* pq = (float*)alloc(8192 * 4);                   // commit partials
  float* ps = (float*)alloc(512 * 4);                    // frec partials (256 used)
  int* flagged = (int*)alloc(8192 * 4);                  // near-tie row worklist
  // Aliases (stream-order-verified liveness):
  //   cnwsT (2MB) -> tmp: live k_transpose..k_fix only.
  //   qb (bf16 qe, 2MB) -> tmp: written by k_dec (AFTER k_fix), read by k_adjq.
  //   xhi/xlo -> qe: qe written by k_dec AFTER k_dist/k_fix consumed xhi/xlo.
  //   chi/clo -> qn: qn otherwise unused (dec2 result never materialized).
  //   pbk/pbv2 -> agg: agg dead between conv1 k_mm (reader) and conv2 k_aggscale (writer).
  unsigned short* qb = (unsigned short*)tmp;
  float* cnwsT = tmp;
  unsigned short* xhi = (unsigned short*)qe;
  unsigned short* xlo = (unsigned short*)(qe + 524288);
  unsigned short* chi = (unsigned short*)qn;
  unsigned short* clo = (unsigned short*)(qn + 262144);
  unsigned long long* pbk = (unsigned long long*)agg;
  float* pbv2 = (float*)(agg + 524288);
  if (ws_size < off) return;  // insufficient scratch (will fail validation loudly)

  hipMemsetAsync(d_ws, 0, zero_bytes, stream);

  // graph structure (norms folded into scan)
  k_degree<<<E / 256, 256, 0, stream>>>(src, dst, bits, dego, degi, scal_u);
  k_scan<<<1, 1024, 0, stream>>>(degi, dego, rowptr, cursor, nsrc, ndst);
  k_scatter<<<E / 256, 256, 0, stream>>>(src, dst, cursor, csr);

  // conv1: h1 = relu((aggscale(feats)) @ W1 + b1)
  k_aggscale<<<N, 128, 0, stream>>>(rowptr, csr, feats, nsrc, ndst, agg);
  k_mm<128, true><<<N / 32, 256, 0, stream>>>(agg, W1, b1, o_h1);

  // VQ: merged l2norm+split (codebook rows [0,C) + h1 rows [C,C+N)), transpose,
  // split-MFMA dist, argmax resolve + near-tie fix
  k_l2nsb<<<(C + N) / 4, 256, 0, stream>>>(codebook, cnws, o_cn, (ushort2*)chi, (ushort2*)clo,
                                           o_h1, xn, (ushort2*)xhi, (ushort2*)xlo);
  k_transpose<<<C / 64, 256, 0, stream>>>(cnws, cnwsT);
  k_dist<<<dim3(C / 128, N / 128), 256, 0, stream>>>(xhi, xlo, chi, clo, o_dist, pbk, pbv2);
  k_q<<<N, 128, 0, stream>>>(pbk, pbv2, cnws, o_h1, o_q, pq, scal_u, flagged);
  k_fix<<<128, 256, 0, stream>>>(scal_u, flagged, xn, cnwsT, cnws, o_h1, o_q, pq);

  // fused decoders: qe (fp32+bf16) + frec partials; qn never materialized
  k_dec<<<N / 32, 256, 0, stream>>>(o_q, dec1W, dec1b, dec2W, dec2b, o_h1, qe, qb, ps);

  // adjacency reconstruction loss: bf16 MFMA over upper-triangle blocks, per-block partials
  k_adjq<<<dim3(N / 128, N / 128), 256, 0, stream>>>(qb, bits, p_sum, p_sq, p_es, p_mn, p_mx);

  // conv2 on quantized_edge + linear head
  k_aggscale<<<N, 128, 0, stream>>>(rowptr, csr, qe, nsrc, ndst, agg);
  k_mm<128, true><<<N / 32, 256, 0, stream>>>(agg, W2, b2, o_h3);
  k_mm<64, false><<<N / 64, 256, 0, stream>>>(o_h3, linW, linb, o_out);

  k_finish<<<1, 1024, 0, stream>>>(p_sum, p_sq, p_es, p_mn, p_mx, pq, ps, scal_u, o_loss);
}

// Round 8
// 516.606 us; speedup vs baseline: 1.1525x; 1.1525x over previous
//
#include <hip/hip_runtime.h>
#include <cstdint>

// Problem constants
constexpr int N = 8192, E = 262144, D = 128, O = 64, C = 4096;

#define DEV __device__ __forceinline__

typedef short s8v __attribute__((ext_vector_type(8)));   // 8 bf16 (4 VGPRs)
typedef float f4v __attribute__((ext_vector_type(4)));   // MFMA 16x16 accumulator

// orderable-uint mapping for float packed argmax
DEV unsigned fmap(float f) {
  unsigned u = __float_as_uint(f);
  return (u & 0x80000000u) ? ~u : (u | 0x80000000u);
}
DEV float funmap(unsigned u) {  // inverse of fmap
  unsigned o = (u & 0x80000000u) ? (u & 0x7FFFFFFFu) : ~u;
  return __uint_as_float(o);
}
DEV unsigned short f2bf(float f) {  // RNE float->bf16 (finite inputs)
  uint32_t b = __float_as_uint(f);
  return (unsigned short)((b + 0x7FFFu + ((b >> 16) & 1u)) >> 16);
}
DEV float bf2f(unsigned short h) { return __uint_as_float((uint32_t)h << 16); }

// ---------------- setup kernels ----------------

__global__ __launch_bounds__(256) void k_degree(const int* __restrict__ src, const int* __restrict__ dst,
    uint32_t* __restrict__ bits, int* __restrict__ dego, int* __restrict__ degi,
    uint32_t* __restrict__ scal_u) {
  int e = blockIdx.x * 256 + threadIdx.x;
  int s = src[e], d = dst[e];
  atomicAdd(&dego[s], 1);
  atomicAdd(&degi[d], 1);
  unsigned idx = (unsigned)s * 8192u + (unsigned)d;
  unsigned bit = 1u << (idx & 31);
  unsigned old = atomicOr(&bits[idx >> 5], bit);
  bool isnew = !(old & bit);
  unsigned long long b = __ballot(isnew);
  if ((threadIdx.x & 63) == 0) atomicAdd(&scal_u[2], (unsigned)__popcll(b));
}

// exclusive scan of deg_in -> row_ptr/cursor; also both degree norms (k_norms folded in)
__global__ __launch_bounds__(1024) void k_scan(const int* __restrict__ degi, const int* __restrict__ dego,
    int* __restrict__ rowptr, int* __restrict__ cursor,
    float* __restrict__ nsrc, float* __restrict__ ndst) {
  __shared__ int sh[1024];
  int tid = threadIdx.x;
  int base = tid * 8;
  int v[8];
  int s = 0;
#pragma unroll
  for (int j = 0; j < 8; ++j) {
    v[j] = degi[base + j];
    int a = dego[base + j];
    nsrc[base + j] = a > 0 ? 1.0f / sqrtf((float)a) : 0.0f;
    ndst[base + j] = v[j] > 0 ? 1.0f / sqrtf((float)v[j]) : 0.0f;
    s += v[j];
  }
  sh[tid] = s;
  __syncthreads();
  for (int off = 1; off < 1024; off <<= 1) {
    int t = (tid >= off) ? sh[tid - off] : 0;
    __syncthreads();
    sh[tid] += t;
    __syncthreads();
  }
  int run = (tid == 0) ? 0 : sh[tid - 1];
#pragma unroll
  for (int j = 0; j < 8; ++j) { rowptr[base + j] = run; cursor[base + j] = run; run += v[j]; }
  if (tid == 1023) rowptr[N] = run;
}

__global__ __launch_bounds__(256) void k_scatter(const int* __restrict__ src, const int* __restrict__ dst,
                                                 int* __restrict__ cursor, int* __restrict__ csr) {
  int e = blockIdx.x * 256 + threadIdx.x;
  int d = dst[e];
  int pos = atomicAdd(&cursor[d], 1);
  csr[pos] = src[e];
}

// fused scale+aggregate: out[row,:] = (sum_e x[src_e,:]*nsrc[src_e]) * ndst[row]
// __fmul_rn/__fadd_rn forbid fma-contraction -> bit-identical across refactors
// (matters for h1 -> argmax stability).
__global__ __launch_bounds__(128) void k_aggscale(const int* __restrict__ rowptr, const int* __restrict__ csr,
    const float* __restrict__ x, const float* __restrict__ nsrc, const float* __restrict__ ndst,
    float* __restrict__ out) {
  int row = blockIdx.x, t = threadIdx.x;
  int e0 = rowptr[row], e1 = rowptr[row + 1];
  float acc = 0.f;
  int e = e0;
  for (; e + 4 <= e1; e += 4) {
    int s0 = csr[e], s1 = csr[e + 1], s2 = csr[e + 2], s3 = csr[e + 3];
    float n0 = nsrc[s0], n1 = nsrc[s1], n2 = nsrc[s2], n3 = nsrc[s3];
    acc = __fadd_rn(acc, __fmul_rn(x[s0 * 128 + t], n0));
    acc = __fadd_rn(acc, __fmul_rn(x[s1 * 128 + t], n1));
    acc = __fadd_rn(acc, __fmul_rn(x[s2 * 128 + t], n2));
    acc = __fadd_rn(acc, __fmul_rn(x[s3 * 128 + t], n3));
  }
  for (; e < e1; ++e) acc = __fadd_rn(acc, __fmul_rn(x[csr[e] * 128 + t], nsrc[csr[e]]));
  out[row * 128 + t] = __fmul_rn(acc, ndst[row]);
}

// merged row-wise l2 normalize + bf16 hi/lo split for BOTH codebook (rows [0,C)) and
// h1 (rows [C,C+N)). Branch is wave-uniform; each path's math is byte-identical to the
// previously-validated k_l2ns, so all outputs are bit-identical. -1 dispatch.
__global__ __launch_bounds__(256) void k_l2nsb(
    const float* __restrict__ cb, float* __restrict__ cnws, float* __restrict__ o_cn,
    ushort2* __restrict__ chi, ushort2* __restrict__ clo,
    const float* __restrict__ h1, float* __restrict__ xn,
    ushort2* __restrict__ xhi, ushort2* __restrict__ xlo) {
  int wave = threadIdx.x >> 6, lane = threadIdx.x & 63;
  int row = blockIdx.x * 4 + wave;           // [0, C+N)
  const float* in;
  float* out_al;
  float* out_extra;
  ushort2* hi;
  ushort2* lo;
  int r;
  if (row < C) {
    in = cb; out_al = cnws; out_extra = o_cn; hi = chi; lo = clo; r = row;
  } else {
    in = h1; out_al = xn; out_extra = nullptr; hi = xhi; lo = xlo; r = row - C;
  }
  float2 v = ((const float2*)in)[r * 64 + lane];
  float ss = v.x * v.x + v.y * v.y;
#pragma unroll
  for (int o = 32; o > 0; o >>= 1) ss += __shfl_xor(ss, o);
  float den = fmaxf(sqrtf(ss), 1e-12f);
  float ox = v.x / den, oy = v.y / den;
  ((float2*)out_al)[r * 64 + lane] = make_float2(ox, oy);
  if (out_extra != nullptr) {
    out_extra[r * 128 + 2 * lane] = ox;
    out_extra[r * 128 + 2 * lane + 1] = oy;
  }
  ushort2 h, l;
  h.x = f2bf(ox); h.y = f2bf(oy);
  l.x = f2bf(ox - bf2f(h.x)); l.y = f2bf(oy - bf2f(h.y));
  hi[r * 64 + lane] = h;
  lo[r * 64 + lane] = l;
}

// codebook transpose: cnws[4096][128] -> cnwsT[128][4096] (coalesced k_fix loads)
__global__ __launch_bounds__(256) void k_transpose(const float* __restrict__ in, float* __restrict__ outT) {
  __shared__ float tl[64][133];
  int t = threadIdx.x;
  int cbase = blockIdx.x * 64;
#pragma unroll
  for (int it = 0; it < 32; ++it) {
    int idx = t + it * 256;
    int r = idx >> 7, k = idx & 127;
    tl[r][k] = in[(cbase + r) * 128 + k];
  }
  __syncthreads();
#pragma unroll
  for (int it = 0; it < 32; ++it) {
    int idx = t + it * 256;
    int k = idx >> 6, c = idx & 63;
    outT[k * 4096 + cbase + c] = tl[c][k];
  }
}

// ---------------- small matmul: out[M,CO] = A[M,128] @ W[128,CO] + bias (+relu) ----------------
template <int CO, bool RELU>
__global__ __launch_bounds__(256, 2) void k_mm(const float* __restrict__ A, const float* __restrict__ W,
    const float* __restrict__ bias, float* __restrict__ out) {
  constexpr int CG = CO / 4;
  constexpr int RG = 256 / CG;
  constexpr int TR = RG * 4;
  constexpr int WIT = (64 * CG) / 256;
  __shared__ __align__(16) float Al[TR * 128];
  __shared__ __align__(16) float Wl[64 * CO];
  int tid = threadIdx.x;
  int cg = tid % CG, rg = tid / CG;
  int rbase = blockIdx.x * TR;
#pragma unroll
  for (int it = 0; it < TR / 8; ++it) {
    int idx = tid + it * 256;
    int r = idx >> 5, c = idx & 31;
    *(float4*)&Al[r * 128 + c * 4] = *(const float4*)&A[(rbase + r) * 128 + c * 4];
  }
  float acc[4][4] = {};
  for (int kc = 0; kc < 128; kc += 64) {
    __syncthreads();
#pragma unroll
    for (int it = 0; it < WIT; ++it) {
      int idx = tid + it * 256;
      int r = idx / CG, c = idx % CG;
      *(float4*)&Wl[r * CO + c * 4] = *(const float4*)&W[(kc + r) * CO + c * 4];
    }
    __syncthreads();
#pragma unroll
    for (int k = 0; k < 64; ++k) {
      float4 w4 = *(const float4*)&Wl[k * CO + cg * 4];
#pragma unroll
      for (int i = 0; i < 4; ++i) {
        float a = Al[(rg * 4 + i) * 128 + kc + k];
        acc[i][0] += a * w4.x; acc[i][1] += a * w4.y; acc[i][2] += a * w4.z; acc[i][3] += a * w4.w;
      }
    }
  }
  float4 b4 = *(const float4*)&bias[cg * 4];
#pragma unroll
  for (int i = 0; i < 4; ++i) {
    float4 o;
    o.x = acc[i][0] + b4.x; o.y = acc[i][1] + b4.y; o.z = acc[i][2] + b4.z; o.w = acc[i][3] + b4.w;
    if (RELU) { o.x = fmaxf(o.x, 0.f); o.y = fmaxf(o.y, 0.f); o.z = fmaxf(o.z, 0.f); o.w = fmaxf(o.w, 0.f); }
    *(float4*)&out[(rbase + rg * 4 + i) * CO + cg * 4] = o;
  }
}

// fused decoders: qe = q@dec1W+b (fp32 + bf16 copy), frec partial of (h1 - (q@dec2W+b))^2.
__global__ __launch_bounds__(256, 3) void k_dec(const float* __restrict__ A,
    const float* __restrict__ W1, const float* __restrict__ b1,
    const float* __restrict__ W2, const float* __restrict__ b2,
    const float* __restrict__ h1, float* __restrict__ qe, unsigned short* __restrict__ qb,
    float* __restrict__ ps) {
  __shared__ __align__(16) float Al[32 * 128];
  __shared__ __align__(16) float Wl1[32 * 128];
  __shared__ __align__(16) float Wl2[32 * 128];
  int tid = threadIdx.x;
  int cg = tid & 31, rg = tid >> 5;
  int rbase = blockIdx.x * 32;
#pragma unroll
  for (int it = 0; it < 4; ++it) {
    int idx = tid + it * 256;
    int r = idx >> 5, c = idx & 31;
    *(float4*)&Al[r * 128 + c * 4] = *(const float4*)&A[(rbase + r) * 128 + c * 4];
  }
  float acc1[4][4] = {}, acc2[4][4] = {};
  for (int kc = 0; kc < 128; kc += 32) {
    __syncthreads();
#pragma unroll
    for (int it = 0; it < 4; ++it) {
      int idx = tid + it * 256;
      int r = idx >> 5, c = idx & 31;
      *(float4*)&Wl1[r * 128 + c * 4] = *(const float4*)&W1[(kc + r) * 128 + c * 4];
      *(float4*)&Wl2[r * 128 + c * 4] = *(const float4*)&W2[(kc + r) * 128 + c * 4];
    }
    __syncthreads();
#pragma unroll
    for (int k = 0; k < 32; ++k) {
      float4 w1 = *(const float4*)&Wl1[k * 128 + cg * 4];
      float4 w2 = *(const float4*)&Wl2[k * 128 + cg * 4];
#pragma unroll
      for (int i = 0; i < 4; ++i) {
        float a = Al[(rg * 4 + i) * 128 + kc + k];
        acc1[i][0] += a * w1.x; acc1[i][1] += a * w1.y; acc1[i][2] += a * w1.z; acc1[i][3] += a * w1.w;
        acc2[i][0] += a * w2.x; acc2[i][1] += a * w2.y; acc2[i][2] += a * w2.z; acc2[i][3] += a * w2.w;
      }
    }
  }
  float4 bb1 = *(const float4*)&b1[cg * 4];
  float4 bb2 = *(const float4*)&b2[cg * 4];
  float s = 0.f;
#pragma unroll
  for (int i = 0; i < 4; ++i) {
    int row = rbase + rg * 4 + i;
    float4 o;
    o.x = acc1[i][0] + bb1.x; o.y = acc1[i][1] + bb1.y;
    o.z = acc1[i][2] + bb1.z; o.w = acc1[i][3] + bb1.w;
    *(float4*)&qe[row * 128 + cg * 4] = o;
    ushort4 ob;
    ob.x = f2bf(o.x); ob.y = f2bf(o.y); ob.z = f2bf(o.z); ob.w = f2bf(o.w);
    *(ushort4*)&qb[row * 128 + cg * 4] = ob;
    float4 h = *(const float4*)&h1[row * 128 + cg * 4];
    float d0 = acc2[i][0] + bb2.x - h.x;
    float d1 = acc2[i][1] + bb2.y - h.y;
    float d2 = acc2[i][2] + bb2.z - h.z;
    float d3 = acc2[i][3] + bb2.w - h.w;
    s += d0 * d0 + d1 * d1 + d2 * d2 + d3 * d3;
  }
#pragma unroll
  for (int o = 32; o > 0; o >>= 1) s += __shfl_xor(s, o);
  __syncthreads();
  float* shp = Al;
  if ((tid & 63) == 0) shp[tid >> 6] = s;
  __syncthreads();
  if (tid == 0) ps[blockIdx.x] = shp[0] + shp[1] + shp[2] + shp[3];
}

// ---------------- dist via split-bf16 MFMA: dist = xn @ cn^T, hi*hi + hi*lo + lo*hi ----------------
// Store epilogue history: LDS-round-trip (r4/r5) -> NaN, banned; nontemporal (r7) ->
// 2x write amplification (WRITE_SIZE 134->262 MB, partial-line RMW at the controller),
// +76us. Scattered 4x64B stores absorbing into L2 and writing back full lines IS the
// fastest validated pattern. Do not touch this epilogue again.
__global__ __launch_bounds__(256) void k_dist(
    const unsigned short* __restrict__ xhi, const unsigned short* __restrict__ xlo,
    const unsigned short* __restrict__ chi, const unsigned short* __restrict__ clo,
    float* __restrict__ dout, unsigned long long* __restrict__ pbk, float* __restrict__ pbv2) {
  int bx = blockIdx.x, by = blockIdx.y;     // bx: codebook tile (32), by: node tile (64)
  int rbase = by * 128, cbase = bx * 128;
  __shared__ __align__(16) unsigned short As[128 * 132];  // +4 pad: conflict-free ds_read_b128
  __shared__ __align__(16) unsigned short Bs[128 * 132];
  int tid = threadIdx.x;
  int wave = tid >> 6, lane = tid & 63;
  int l15 = lane & 15, quad = lane >> 4;
  int wr = wave * 32;

  // stage A-hi and B-hi
#pragma unroll
  for (int it = 0; it < 8; ++it) {
    int idx = tid + it * 256;
    int r = idx >> 4, ch = idx & 15;
    *(s8v*)&As[r * 132 + ch * 8] = *(const s8v*)&xhi[(rbase + r) * 128 + ch * 8];
    *(s8v*)&Bs[r * 132 + ch * 8] = *(const s8v*)&chi[(cbase + r) * 128 + ch * 8];
  }
  __syncthreads();
  s8v ah[2][4], al[2][4];
#pragma unroll
  for (int rt = 0; rt < 2; ++rt)
#pragma unroll
    for (int kq = 0; kq < 4; ++kq)
      ah[rt][kq] = *(const s8v*)&As[(wr + rt * 16 + l15) * 132 + kq * 32 + quad * 8];
  __syncthreads();           // all waves have a-hi frags in regs -> safe to overwrite As
#pragma unroll
  for (int it = 0; it < 8; ++it) {
    int idx = tid + it * 256;
    int r = idx >> 4, ch = idx & 15;
    *(s8v*)&As[r * 132 + ch * 8] = *(const s8v*)&xlo[(rbase + r) * 128 + ch * 8];
  }
  __syncthreads();
#pragma unroll
  for (int rt = 0; rt < 2; ++rt)
#pragma unroll
    for (int kq = 0; kq < 4; ++kq)
      al[rt][kq] = *(const s8v*)&As[(wr + rt * 16 + l15) * 132 + kq * 32 + quad * 8];

  f4v acc[2][8];
#pragma unroll
  for (int rt = 0; rt < 2; ++rt)
#pragma unroll
    for (int ct = 0; ct < 8; ++ct) acc[rt][ct] = {0.f, 0.f, 0.f, 0.f};

  // pass 1+2: (a_hi + a_lo) x B_hi
#pragma unroll
  for (int ct = 0; ct < 8; ++ct) {
    s8v b[4];
#pragma unroll
    for (int kq = 0; kq < 4; ++kq)
      b[kq] = *(const s8v*)&Bs[(ct * 16 + l15) * 132 + kq * 32 + quad * 8];
#pragma unroll
    for (int rt = 0; rt < 2; ++rt)
#pragma unroll
      for (int kq = 0; kq < 4; ++kq) {
        acc[rt][ct] = __builtin_amdgcn_mfma_f32_16x16x32_bf16(ah[rt][kq], b[kq], acc[rt][ct], 0, 0, 0);
        acc[rt][ct] = __builtin_amdgcn_mfma_f32_16x16x32_bf16(al[rt][kq], b[kq], acc[rt][ct], 0, 0, 0);
      }
  }
  __syncthreads();           // all waves done with B_hi -> restage
#pragma unroll
  for (int it = 0; it < 8; ++it) {
    int idx = tid + it * 256;
    int r = idx >> 4, ch = idx & 15;
    *(s8v*)&Bs[r * 132 + ch * 8] = *(const s8v*)&clo[(cbase + r) * 128 + ch * 8];
  }
  __syncthreads();
  // pass 3: a_hi x B_lo
#pragma unroll
  for (int ct = 0; ct < 8; ++ct) {
    s8v b[4];
#pragma unroll
    for (int kq = 0; kq < 4; ++kq)
      b[kq] = *(const s8v*)&Bs[(ct * 16 + l15) * 132 + kq * 32 + quad * 8];
#pragma unroll
    for (int rt = 0; rt < 2; ++rt)
#pragma unroll
      for (int kq = 0; kq < 4; ++kq)
        acc[rt][ct] = __builtin_amdgcn_mfma_f32_16x16x32_bf16(ah[rt][kq], b[kq], acc[rt][ct], 0, 0, 0);
  }

  // epilogue: store dist + per-lane top2 over the 8 cols each (rt,reg)-row sees
  float b1v[2][4], b2v[2][4];
  unsigned c1v[2][4];
#pragma unroll
  for (int rt = 0; rt < 2; ++rt)
#pragma unroll
    for (int reg = 0; reg < 4; ++reg) { b1v[rt][reg] = -3.4e38f; b2v[rt][reg] = -3.4e38f; c1v[rt][reg] = 0; }
#pragma unroll
  for (int rt = 0; rt < 2; ++rt)
#pragma unroll
    for (int ct = 0; ct < 8; ++ct)
#pragma unroll
      for (int reg = 0; reg < 4; ++reg) {
        float v = acc[rt][ct][reg];
        int row = rbase + wr + rt * 16 + quad * 4 + reg;
        int col = cbase + ct * 16 + l15;
        dout[(size_t)row * 4096 + col] = v;   // scalar store: dist base is float-misaligned
        if (v > b1v[rt][reg]) { b2v[rt][reg] = b1v[rt][reg]; b1v[rt][reg] = v; c1v[rt][reg] = (unsigned)col; }
        else if (v > b2v[rt][reg]) b2v[rt][reg] = v;  // strict > keeps lowest col (np tie rule)
      }
  __syncthreads();           // As/Bs frag reads all done -> reuse as scratch
  unsigned long long* sck = (unsigned long long*)As;  // [128][16] keys, 16 KB
  float* scv = (float*)Bs;                            // [128][16] 2nd-best values, 8 KB
#pragma unroll
  for (int rt = 0; rt < 2; ++rt)
#pragma unroll
    for (int reg = 0; reg < 4; ++reg) {
      int rloc = wr + rt * 16 + quad * 4 + reg;
      sck[rloc * 16 + l15] =
          (((unsigned long long)fmap(b1v[rt][reg])) << 32) |
          (unsigned long long)(0xFFFFFFFFu - c1v[rt][reg]);
      scv[rloc * 16 + l15] = b2v[rt][reg];
    }
  __syncthreads();
  if (tid < 128) {
    unsigned long long m = 0ull;
#pragma unroll
    for (int l = 0; l < 16; ++l) {
      unsigned long long t = sck[tid * 16 + l];
      m = t > m ? t : m;
    }
    float v2 = -3.4e38f;
#pragma unroll
    for (int l = 0; l < 16; ++l) {
      unsigned long long k = sck[tid * 16 + l];
      float c = (k == m) ? scv[tid * 16 + l] : funmap((unsigned)(k >> 32));
      v2 = fmaxf(v2, c);
    }
    pbk[(size_t)(rbase + tid) * 32 + bx] = m;
    pbv2[(size_t)(rbase + tid) * 32 + bx] = v2;
  }
}

// resolve argmax; ALWAYS finalize with candidate col; near-ties (gap < 2e-4) get appended
// to a worklist for k_fix (round-1 lesson: in-block uncoalesced recompute -> 160us tail).
__global__ __launch_bounds__(128) void k_q(const unsigned long long* __restrict__ pbk,
    const float* __restrict__ pbv2, const float* __restrict__ cnws,
    const float* __restrict__ h1, float* __restrict__ qout, float* __restrict__ pq,
    uint32_t* __restrict__ scal_u, int* __restrict__ flagged) {
  int row = blockIdx.x, t = threadIdx.x;
  int e = t & 31;
  unsigned long long k = pbk[(size_t)row * 32 + e];
  float v2l = pbv2[(size_t)row * 32 + e];
  unsigned long long m = k;
#pragma unroll
  for (int o = 32; o > 0; o >>= 1) {
    unsigned long long s = __shfl_xor(m, o);
    m = s > m ? s : m;
  }
  float cand = (k == m) ? v2l : funmap((unsigned)(k >> 32));
#pragma unroll
  for (int o = 32; o > 0; o >>= 1) cand = fmaxf(cand, __shfl_xor(cand, o));
  float gap = funmap((unsigned)(m >> 32)) - cand;
  if (gap < 2e-4f && t == 0) {
    unsigned idx = atomicAdd(&scal_u[3], 1u);
    flagged[idx] = row;
  }
  int col = (int)(0xFFFFFFFFu - (unsigned)(m & 0xFFFFFFFFull));
  float q = cnws[col * 128 + t];
  qout[row * 128 + t] = q;
  float dd = q - h1[row * 128 + t];
  float ss = dd * dd;
#pragma unroll
  for (int o = 32; o > 0; o >>= 1) ss += __shfl_xor(ss, o);
  __shared__ float p[2];
  if ((t & 63) == 0) p[t >> 6] = ss;
  __syncthreads();
  if (t == 0) pq[row] = p[0] + p[1];
}

// exact fp32 argmax for flagged rows, coalesced via transposed codebook.
__global__ __launch_bounds__(256) void k_fix(const uint32_t* __restrict__ scal_u,
    const int* __restrict__ flagged, const float* __restrict__ xn,
    const float* __restrict__ cnwsT, const float* __restrict__ cnws,
    const float* __restrict__ h1, float* __restrict__ qout, float* __restrict__ pq) {
  int nf = (int)scal_u[3];
  int t = threadIdx.x;
  __shared__ float xr[128];
  __shared__ unsigned long long bw4[4];
  __shared__ float pp[2];
  for (int i = blockIdx.x; i < nf; i += gridDim.x) {
    int row = flagged[i];
    __syncthreads();
    if (t < 128) xr[t] = xn[row * 128 + t];
    __syncthreads();
    float s[16];
#pragma unroll
    for (int j = 0; j < 16; ++j) s[j] = 0.f;
    for (int k = 0; k < 128; ++k) {
      float xv = xr[k];
      const float* cp = &cnwsT[k * 4096 + t];
#pragma unroll
      for (int j = 0; j < 16; ++j) s[j] = fmaf(xv, cp[j * 256], s[j]);
    }
    unsigned long long best = 0ull;
#pragma unroll
    for (int j = 0; j < 16; ++j) {
      unsigned c = (unsigned)(j * 256 + t);
      unsigned long long key = (((unsigned long long)fmap(s[j])) << 32) |
                               (unsigned long long)(0xFFFFFFFFu - c);
      if (key > best) best = key;
    }
#pragma unroll
    for (int o = 32; o > 0; o >>= 1) {
      unsigned long long s2 = __shfl_xor(best, o);
      best = s2 > best ? s2 : best;
    }
    if ((t & 63) == 0) bw4[t >> 6] = best;
    __syncthreads();
    unsigned long long b0 = bw4[0] > bw4[1] ? bw4[0] : bw4[1];
    unsigned long long b1 = bw4[2] > bw4[3] ? bw4[2] : bw4[3];
    best = b0 > b1 ? b0 : b1;
    int col = (int)(0xFFFFFFFFu - (unsigned)(best & 0xFFFFFFFFull));
    if (t < 128) {
      float q = cnws[col * 128 + t];
      qout[(size_t)row * 128 + t] = q;
      float dd = q - h1[row * 128 + t];
      float ss = dd * dd;
#pragma unroll
      for (int o = 32; o > 0; o >>= 1) ss += __shfl_xor(ss, o);
      if ((t & 63) == 0) pp[t >> 6] = ss;
    }
    __syncthreads();
    if (t == 0) pq[row] = pp[0] + pp[1];
  }
}

// ---------------- adjq via bf16 MFMA: fused loss reductions over qe @ qe^T ----------------
__global__ __launch_bounds__(256) void k_adjq(const unsigned short* __restrict__ qb,
    const uint32_t* __restrict__ bits,
    double* __restrict__ p_sum, double* __restrict__ p_sq, double* __restrict__ p_es,
    float* __restrict__ p_mn, float* __restrict__ p_mx) {
  int bx = blockIdx.x, by = blockIdx.y;
  int pid = by * gridDim.x + bx;
  int tid = threadIdx.x;
  if (bx < by) {
    if (tid == 0) {
      p_sum[pid] = 0.0; p_sq[pid] = 0.0; p_es[pid] = 0.0;
      p_mn[pid] = 3.4e38f; p_mx[pid] = -3.4e38f;
    }
    return;
  }
  int rbase = by * 128, cbase = bx * 128;
  __shared__ unsigned short Ab[128 * 132];
  __shared__ unsigned short Bb[128 * 132];
#pragma unroll
  for (int it = 0; it < 8; ++it) {
    int idx = tid + it * 256;
    int r = idx >> 4, ch = idx & 15;
    *(s8v*)&Ab[r * 132 + ch * 8] = *(const s8v*)&qb[(rbase + r) * 128 + ch * 8];
    *(s8v*)&Bb[r * 132 + ch * 8] = *(const s8v*)&qb[(cbase + r) * 128 + ch * 8];
  }
  __syncthreads();
  int wave = tid >> 6, lane = tid & 63;
  int l15 = lane & 15, quad = lane >> 4;
  int wr = wave * 32;
  f4v acc[2][8];
#pragma unroll
  for (int rt = 0; rt < 2; ++rt)
#pragma unroll
    for (int ct = 0; ct < 8; ++ct) acc[rt][ct] = {0.f, 0.f, 0.f, 0.f};
  s8v a[2][4];
#pragma unroll
  for (int rt = 0; rt < 2; ++rt)
#pragma unroll
    for (int kq = 0; kq < 4; ++kq)
      a[rt][kq] = *(const s8v*)&Ab[(wr + rt * 16 + l15) * 132 + kq * 32 + quad * 8];
#pragma unroll
  for (int ct = 0; ct < 8; ++ct) {
    s8v b[4];
#pragma unroll
    for (int kq = 0; kq < 4; ++kq)
      b[kq] = *(const s8v*)&Bb[(ct * 16 + l15) * 132 + kq * 32 + quad * 8];
#pragma unroll
    for (int rt = 0; rt < 2; ++rt)
#pragma unroll
      for (int kq = 0; kq < 4; ++kq)
        acc[rt][ct] = __builtin_amdgcn_mfma_f32_16x16x32_bf16(a[rt][kq], b[kq], acc[rt][ct], 0, 0, 0);
  }
  __syncthreads();
  uint32_t* bl = (uint32_t*)Ab;
  uint32_t* blT = bl + 512;
#pragma unroll
  for (int it = 0; it < 2; ++it) {
    int idx = tid + it * 256;
    int r = idx >> 2, wq = idx & 3;
    bl[idx] = bits[(rbase + r) * 256 + (cbase >> 5) + wq];
    blT[idx] = bits[(cbase + r) * 256 + (rbase >> 5) + wq];
  }
  __syncthreads();
  float lsum = 0.f, lsq = 0.f, les = 0.f;
  float lmin = 3.4e38f, lmax = -3.4e38f;
  bool diag = (bx == by);
#pragma unroll
  for (int rt = 0; rt < 2; ++rt)
#pragma unroll
    for (int ct = 0; ct < 8; ++ct)
#pragma unroll
      for (int reg = 0; reg < 4; ++reg) {
        int lr = wr + rt * 16 + quad * 4 + reg;
        int lc = ct * 16 + l15;
        if (diag && lc < lr) continue;
        float v = acc[rt][ct][reg];
        bool ondiag = diag && (lc == lr);
        float wgt = ondiag ? 1.f : 2.f;
        lsum += wgt * v;
        lsq += wgt * v * v;
        lmin = fminf(lmin, v);
        lmax = fmaxf(lmax, v);
        unsigned eb = (bl[lr * 4 + (lc >> 5)] >> (lc & 31)) & 1u;
        if (!ondiag) eb += (blT[lc * 4 + (lr >> 5)] >> (lr & 31)) & 1u;
        if (eb) les += (float)eb * v;
      }
  double dsum = (double)lsum, dsq = (double)lsq, des = (double)les;
#pragma unroll
  for (int o = 32; o > 0; o >>= 1) {
    dsum += __shfl_xor(dsum, o);
    dsq += __shfl_xor(dsq, o);
    des += __shfl_xor(des, o);
    lmin = fminf(lmin, __shfl_xor(lmin, o));
    lmax = fmaxf(lmax, __shfl_xor(lmax, o));
  }
  double* shd = (double*)Bb;
  float* shf = (float*)(shd + 12);
  if (lane == 0) {
    shd[wave * 3 + 0] = dsum; shd[wave * 3 + 1] = dsq; shd[wave * 3 + 2] = des;
    shf[wave * 2 + 0] = lmin; shf[wave * 2 + 1] = lmax;
  }
  __syncthreads();
  if (tid == 0) {
    double s = 0.0, q = 0.0, e = 0.0;
    float m0 = 3.4e38f, m1 = -3.4e38f;
#pragma unroll
    for (int w0 = 0; w0 < 4; ++w0) {
      s += shd[w0 * 3 + 0]; q += shd[w0 * 3 + 1]; e += shd[w0 * 3 + 2];
      m0 = fminf(m0, shf[w0 * 2 + 0]); m1 = fmaxf(m1, shf[w0 * 2 + 1]);
    }
    p_sum[pid] = s; p_sq[pid] = q; p_es[pid] = e;
    p_mn[pid] = m0; p_mx[pid] = m1;
  }
}

__global__ __launch_bounds__(1024) void k_finish(const double* __restrict__ p_sum,
    const double* __restrict__ p_sq, const double* __restrict__ p_es,
    const float* __restrict__ p_mn, const float* __restrict__ p_mx,
    const float* __restrict__ pq, const float* __restrict__ ps,
    const uint32_t* __restrict__ scal_u, float* __restrict__ o_loss) {
  int tid = threadIdx.x;
  double sum = 0.0, sq = 0.0, es = 0.0, commit = 0.0, frec = 0.0;
  float mn = 3.4e38f, mx = -3.4e38f;
  for (int i = tid; i < 4096; i += 1024) {
    sum += p_sum[i]; sq += p_sq[i]; es += p_es[i];
    mn = fminf(mn, p_mn[i]); mx = fmaxf(mx, p_mx[i]);
  }
  for (int i = tid; i < 8192; i += 1024) commit += (double)pq[i];
  if (tid < 256) frec = (double)ps[tid];   // k_dec emits 256 partials
#pragma unroll
  for (int o = 32; o > 0; o >>= 1) {
    sum += __shfl_xor(sum, o); sq += __shfl_xor(sq, o); es += __shfl_xor(es, o);
    commit += __shfl_xor(commit, o); frec += __shfl_xor(frec, o);
    mn = fminf(mn, __shfl_xor(mn, o)); mx = fmaxf(mx, __shfl_xor(mx, o));
  }
  __shared__ double shd[16][5];
  __shared__ float shf[16][2];
  int wave = tid >> 6, lane = tid & 63;
  if (lane == 0) {
    shd[wave][0] = sum; shd[wave][1] = sq; shd[wave][2] = es;
    shd[wave][3] = commit; shd[wave][4] = frec;
    shf[wave][0] = mn; shf[wave][1] = mx;
  }
  __syncthreads();
  if (tid == 0) {
    double s = 0, q = 0, e = 0, c = 0, f = 0;
    float m0 = 3.4e38f, m1 = -3.4e38f;
    for (int w0 = 0; w0 < 16; ++w0) {
      s += shd[w0][0]; q += shd[w0][1]; e += shd[w0][2]; c += shd[w0][3]; f += shd[w0][4];
      m0 = fminf(m0, shf[w0][0]); m1 = fmaxf(m1, shf[w0][1]);
    }
    double mnd = (double)m0, mxd = (double)m1, U = (double)scal_u[2];
    const double N2 = 67108864.0;
    double scl = 1.0 / (mxd - mnd);
    double mean = (scl * scl * (q - 2.0 * mnd * s + mnd * mnd * N2) - 2.0 * scl * (e - mnd * U) + U) / N2;
    *o_loss = (float)(f / 1048576.0 + sqrt(mean) + 0.25 * c / 1048576.0);
  }
}

extern "C" void kernel_launch(void* const* d_in, const int* in_sizes, int n_in,
                              void* d_out, int out_size, void* d_ws, size_t ws_size,
                              hipStream_t stream) {
  (void)in_sizes; (void)n_in; (void)out_size;
  const float* feats = (const float*)d_in[0];
  const int* src = (const int*)d_in[1];
  const int* dst = (const int*)d_in[2];
  const float* W1 = (const float*)d_in[3];
  const float* b1 = (const float*)d_in[4];
  const float* W2 = (const float*)d_in[5];
  const float* b2 = (const float*)d_in[6];
  const float* dec1W = (const float*)d_in[7];
  const float* dec1b = (const float*)d_in[8];
  const float* dec2W = (const float*)d_in[9];
  const float* dec2b = (const float*)d_in[10];
  const float* linW = (const float*)d_in[11];
  const float* linb = (const float*)d_in[12];
  const float* codebook = (const float*)d_in[13];

  float* out = (float*)d_out;
  float* o_h1 = out;                    // [N,128]
  float* o_q = out + 1048576;           // [N,128]
  float* o_h3 = out + 2097152;          // [N,128]
  float* o_out = out + 3145728;         // [N,64]
  float* o_loss = out + 3670016;        // scalar
  float* o_dist = out + 3670017;        // [N,4096] (float-misaligned base!)
  float* o_cn = out + 37224449;         // [C,128]  (float-misaligned base!)

  char* w = (char*)d_ws;
  size_t off = 0;
  auto alloc = [&](size_t b) { char* p = w + off; off = (off + b + 255) & ~(size_t)255; return p; };
  uint32_t* bits = (uint32_t*)alloc(8388608);            // N*N/8 adjacency bitmask
  int* dego = (int*)alloc(N * 4);
  int* degi = (int*)alloc(N * 4);
  uint32_t* scal_u = (uint32_t*)alloc(256);              // [2]=U unique edges, [3]=flag count
  size_t zero_bytes = off;                               // everything above must start at 0
  int* rowptr = (int*)alloc((N + 1) * 4);
  int* cursor = (int*)alloc(N * 4);
  int* csr = (int*)alloc(E * 4);
  float* nsrc = (float*)alloc(N * 4);
  float* ndst = (float*)alloc(N * 4);
  float* tmp = (float*)alloc((size_t)N * D * 4);         // hosts cnwsT + qb (disjoint live ranges)
  float* agg = (float*)alloc((size_t)N * D * 4);
  float* xn = (float*)alloc((size_t)N * D * 4);
  float* cnws = (float*)alloc((size_t)C * D * 4);        // aligned copy of cn
  float* qe = (float*)alloc((size_t)N * D * 4);
  float* qn = (float*)alloc((size_t)N * D * 4);          // hosts chi/clo alias only
  double* p_sum = (double*)alloc(4096 * 8);              // adjq per-block partials
  double* p_sq = (double*)alloc(4096 * 8);
  double* p_es = (double*)alloc(4096 * 8);
  float* p_mn = (float*)alloc(4096 * 4);
  float* p_mx = (float*)alloc(4096 * 4);
  float* pq = (float*)alloc(8192 * 4);                   // commit partials
  float* ps = (float*)alloc(512 * 4);                    // frec partials (256 used)
  int* flagged = (int*)alloc(8192 * 4);                  // near-tie row worklist
  // Aliases (stream-order-verified liveness):
  //   cnwsT (2MB) -> tmp: live k_transpose..k_fix only.
  //   qb (bf16 qe, 2MB) -> tmp: written by k_dec (AFTER k_fix), read by k_adjq.
  //   xhi/xlo -> qe: qe written by k_dec AFTER k_dist/k_fix consumed xhi/xlo.
  //   chi/clo -> qn: qn otherwise unused (dec2 result never materialized).
  //   pbk/pbv2 -> agg: agg dead between conv1 k_mm (reader) and conv2 k_aggscale (writer).
  unsigned short* qb = (unsigned short*)tmp;
  float* cnwsT = tmp;
  unsigned short* xhi = (unsigned short*)qe;
  unsigned short* xlo = (unsigned short*)(qe + 524288);
  unsigned short* chi = (unsigned short*)qn;
  unsigned short* clo = (unsigned short*)(qn + 262144);
  unsigned long long* pbk = (unsigned long long*)agg;
  float* pbv2 = (float*)(agg + 524288);
  if (ws_size < off) return;  // insufficient scratch (will fail validation loudly)

  hipMemsetAsync(d_ws, 0, zero_bytes, stream);

  // graph structure (norms folded into scan)
  k_degree<<<E / 256, 256, 0, stream>>>(src, dst, bits, dego, degi, scal_u);
  k_scan<<<1, 1024, 0, stream>>>(degi, dego, rowptr, cursor, nsrc, ndst);
  k_scatter<<<E / 256, 256, 0, stream>>>(src, dst, cursor, csr);

  // conv1: h1 = relu((aggscale(feats)) @ W1 + b1)
  k_aggscale<<<N, 128, 0, stream>>>(rowptr, csr, feats, nsrc, ndst, agg);
  k_mm<128, true><<<N / 32, 256, 0, stream>>>(agg, W1, b1, o_h1);

  // VQ: merged l2norm+split (codebook rows [0,C) + h1 rows [C,C+N)), transpose,
  // split-MFMA dist, argmax resolve + near-tie fix
  k_l2nsb<<<(C + N) / 4, 256, 0, stream>>>(codebook, cnws, o_cn, (ushort2*)chi, (ushort2*)clo,
                                           o_h1, xn, (ushort2*)xhi, (ushort2*)xlo);
  k_transpose<<<C / 64, 256, 0, stream>>>(cnws, cnwsT);
  k_dist<<<dim3(C / 128, N / 128), 256, 0, stream>>>(xhi, xlo, chi, clo, o_dist, pbk, pbv2);
  k_q<<<N, 128, 0, stream>>>(pbk, pbv2, cnws, o_h1, o_q, pq, scal_u, flagged);
  k_fix<<<128, 256, 0, stream>>>(scal_u, flagged, xn, cnwsT, cnws, o_h1, o_q, pq);

  // fused decoders: qe (fp32+bf16) + frec partials; qn never materialized
  k_dec<<<N / 32, 256, 0, stream>>>(o_q, dec1W, dec1b, dec2W, dec2b, o_h1, qe, qb, ps);

  // adjacency reconstruction loss: bf16 MFMA over upper-triangle blocks, per-block partials
  k_adjq<<<dim3(N / 128, N / 128), 256, 0, stream>>>(qb, bits, p_sum, p_sq, p_es, p_mn, p_mx);

  // conv2 on quantized_edge + linear head
  k_aggscale<<<N, 128, 0, stream>>>(rowptr, csr, qe, nsrc, ndst, agg);
  k_mm<128, true><<<N / 32, 256, 0, stream>>>(agg, W2, b2, o_h3);
  k_mm<64, false><<<N / 64, 256, 0, stream>>>(o_h3, linW, linb, o_out);

  k_finish<<<1, 1024, 0, stream>>>(p_sum, p_sq, p_es, p_mn, p_mx, pq, ps, scal_u, o_loss);
}